// Round 2
// baseline (777.310 us; speedup 1.0000x reference)
//
#include <hip/hip_runtime.h>
#include <stdint.h>

// Problem: B=16, D=512, H=64, W=64, M=512, N=B*H*W=65536
// out layout (floats):
//   updated_query  [0, 67108864)          (16,1024,64,64)
//   updated_memory [67108864, 67371008)   (512,512)
//   score_q        [67371008, 100925440)  (65536,512)
//   score_m        [100925440, 134479872) (65536,512)
//   separateness   [134479872]
//   compactness    [134479873]
#define UM_OFF   67108864u
#define SQ_OFF   67371008u
#define SM_OFF   100925440u
#define SEP_OFF  134479872u
#define COMP_OFF 134479873u

// ws layout (bytes) — total ~66 MiB
#define WS_QBF   0u           // 65536*512 bf16 = 64 MiB; reused in-place as smbf by K4
#define WS_KBF   67108864u    // keys bf16 (M,D)        512 KiB
#define WS_KTBF  67633152u    // keysT bf16 (D,M)       512 KiB
#define WS_QU    68157440u    // query_update f32 (512,512)  1 MiB
#define WS_CSUM  69206016u    // col sums f32 (512)

typedef __attribute__((ext_vector_type(8))) short short8v;
typedef __attribute__((ext_vector_type(4))) float float4v;
typedef __attribute__((ext_vector_type(4))) unsigned short ushort4v;

__device__ __forceinline__ unsigned short f2bf(float f) {
  union { float f; uint32_t u; } v; v.f = f;
  return (unsigned short)((v.u + 0x7fffu + ((v.u >> 16) & 1u)) >> 16);
}
__device__ __forceinline__ float bf2f(unsigned short s) {
  union { uint32_t u; float f; } v; v.u = ((uint32_t)s) << 16;
  return v.f;
}

#define GLDS16(gp, lp) __builtin_amdgcn_global_load_lds( \
    (__attribute__((address_space(1))) const void*)(gp), \
    (__attribute__((address_space(3))) void*)(lp), 16, 0, 0)

// ---------------- K0: prep (bf16 keys, keysT, zero accumulators) ----------------
__global__ void k0_prep(const float* __restrict__ keys, unsigned short* __restrict__ kbf,
                        unsigned short* __restrict__ ktbf, float* __restrict__ qu,
                        float* __restrict__ csum, float* __restrict__ out) {
  int i = blockIdx.x * 256 + threadIdx.x;   // 262144 threads exactly
  kbf[i] = f2bf(keys[i]);
  int d = i >> 9, m = i & 511;              // ktbf[i] = keysT[d][m] = keys[m][d]
  ktbf[i] = f2bf(keys[(size_t)m * 512 + d]);
  qu[i] = 0.0f;
  if (i < 512) csum[i] = 0.0f;
  if (i < 2) out[SEP_OFF + i] = 0.0f;
}

// ---------------- K1: per-pixel L2 norm, write updated_query[:, :512], write qbf ----------------
// one block per (b,h): tile is query[b, 0:512, h, 0:64]
__global__ __launch_bounds__(256) void k1_norm(const float* __restrict__ query,
                                               float* __restrict__ out,
                                               unsigned short* __restrict__ qbf) {
  __shared__ unsigned short vals[512 * 65];  // [d][w], pad 65 (bank spread)
  __shared__ float pp[4][64];
  __shared__ float rs[64];
  int bh = blockIdx.x;                       // b*64 + h
  int b = bh >> 6, h = bh & 63;
  int tid = threadIdx.x;
  int w = tid & 63, dg = tid >> 6;
  const float* src = query + ((size_t)(b * 512) * 64 + h) * 64 + w;  // + d*4096
  float ss = 0.f;
  #pragma unroll 4
  for (int i = 0; i < 128; ++i) {
    int d = dg * 128 + i;
    float v = src[(size_t)d * 4096];
    ss += v * v;
    vals[d * 65 + w] = f2bf(v);
  }
  pp[dg][w] = ss;
  __syncthreads();
  if (tid < 64) {
    float s = pp[0][tid] + pp[1][tid] + pp[2][tid] + pp[3][tid];
    rs[tid] = 1.0f / fmaxf(sqrtf(s), 1e-12f);
  }
  __syncthreads();
  // phase B: updated_query[b, d, h, w] = qn (coalesced)
  float rw_ = rs[w];
  float* dst = out + ((size_t)(b * 1024) * 64 + h) * 64 + w;
  #pragma unroll 4
  for (int i = 0; i < 128; ++i) {
    int d = dg * 128 + i;
    dst[(size_t)d * 4096] = bf2f(vals[d * 65 + w]) * rw_;
  }
  // phase C: qbf[r][d] transposed write, r = bh*64 + w2
  int w2 = tid >> 2, dc = tid & 3;
  float rw = rs[w2];
  unsigned short* qrow = qbf + ((size_t)bh * 64 + w2) * 512;
  #pragma unroll
  for (int g = 0; g < 8; ++g) {
    int d0 = g * 64 + dc * 16;
    short8v pk0, pk1;
    #pragma unroll
    for (int jj = 0; jj < 8; ++jj) {
      pk0[jj] = (short)f2bf(bf2f(vals[(d0 + jj) * 65 + w2]) * rw);
      pk1[jj] = (short)f2bf(bf2f(vals[(d0 + 8 + jj) * 65 + w2]) * rw);
    }
    *(short8v*)(qrow + d0) = pk0;
    *(short8v*)(qrow + d0 + 8) = pk1;
  }
}

// ---------------- K3: GEMM1  E = exp(q @ keys^T / scale), col-sum atomics ----------------
// C[r][m], A=qbf (65536x512), B=kbf (512x512, N x K row-major). 128x128 tile, BK=32.
__global__ __launch_bounds__(256) void k3_gemm1(
    const unsigned short* __restrict__ qbf, const unsigned short* __restrict__ kbf,
    float* __restrict__ out, float* __restrict__ csum) {
  __shared__ unsigned short As[128 * 32];
  __shared__ unsigned short Bs[128 * 32];
  int bid = blockIdx.x;                          // 2048
  int bm = (bid & 7) * 64 + (bid >> 5);          // siblings (same XCD) share B panel
  int bn = (bid >> 3) & 3;
  int tid = threadIdx.x;
  int lane = tid & 63, wid = tid >> 6;
  int wr = wid >> 1, wc = wid & 1;
  float4v acc[4][4];
  #pragma unroll
  for (int m = 0; m < 4; ++m)
    #pragma unroll
    for (int n = 0; n < 4; ++n) acc[m][n] = (float4v){0.f, 0.f, 0.f, 0.f};
  const unsigned short* Abase = qbf + (size_t)bm * 128 * 512;
  const unsigned short* Bbase = kbf + (size_t)bn * 128 * 512;
  int u0 = wid * 128 + lane, u1 = u0 + 64;       // 16B staging units
  int ra0 = u0 >> 2, ca0 = (u0 & 3) * 8;
  int ra1 = u1 >> 2, ca1 = (u1 & 3) * 8;
  for (int kt = 0; kt < 16; ++kt) {
    const unsigned short* Ak = Abase + kt * 32;
    const unsigned short* Bk = Bbase + kt * 32;
    GLDS16(Ak + (size_t)ra0 * 512 + ca0, &As[(wid * 2 + 0) * 512]);
    GLDS16(Ak + (size_t)ra1 * 512 + ca1, &As[(wid * 2 + 1) * 512]);
    GLDS16(Bk + (size_t)ra0 * 512 + ca0, &Bs[(wid * 2 + 0) * 512]);
    GLDS16(Bk + (size_t)ra1 * 512 + ca1, &Bs[(wid * 2 + 1) * 512]);
    __syncthreads();
    short8v a[4], b[4];
    const unsigned short* pa = As + (wr * 64 + (lane & 15)) * 32 + (lane >> 4) * 8;
    const unsigned short* pb = Bs + (wc * 64 + (lane & 15)) * 32 + (lane >> 4) * 8;
    #pragma unroll
    for (int m = 0; m < 4; ++m) a[m] = *(const short8v*)(pa + m * 512);
    #pragma unroll
    for (int n = 0; n < 4; ++n) b[n] = *(const short8v*)(pb + n * 512);
    #pragma unroll
    for (int m = 0; m < 4; ++m)
      #pragma unroll
      for (int n = 0; n < 4; ++n)
        acc[m][n] = __builtin_amdgcn_mfma_f32_16x16x32_bf16(a[m], b[n], acc[m][n], 0, 0, 0);
    __syncthreads();
  }
  // epilogue: E = exp(logit/scale) into score_q region; column partial sums
  float* E = out + SQ_OFF;
  const float inv_scale = 0.44194173824159216f;  // 1/(sqrt(512)*0.1)
  int r0 = bm * 128 + wr * 64 + (lane >> 4) * 4;
  int c0 = bn * 128 + wc * 64 + (lane & 15);
  float cs[4] = {0.f, 0.f, 0.f, 0.f};
  #pragma unroll
  for (int m = 0; m < 4; ++m)
    #pragma unroll
    for (int n = 0; n < 4; ++n)
      #pragma unroll
      for (int j = 0; j < 4; ++j) {
        float v = __expf(acc[m][n][j] * inv_scale);
        E[(size_t)(r0 + m * 16 + j) * 512 + (c0 + n * 16)] = v;
        cs[n] += v;
      }
  #pragma unroll
  for (int n = 0; n < 4; ++n) {
    float v = cs[n];
    v += __shfl_xor(v, 16);
    v += __shfl_xor(v, 32);
    if ((lane >> 4) == 0) atomicAdd(&csum[c0 + n * 16], v);
  }
}

// ---------------- K4: per-row pass ----------------
// smbf ALIASES qbf: row r of q is fully consumed before being overwritten by score_m row r.
__global__ __launch_bounds__(256) void k4_rows(
    float* __restrict__ out, const float* __restrict__ csum,
    unsigned short* __restrict__ qsm, const float* __restrict__ keys,
    float* __restrict__ qu) {
  int tid = threadIdx.x;
  int lane = tid & 63, wid = tid >> 6;
  float4v c0 = *(const float4v*)(csum + lane * 4);
  float4v c1 = *(const float4v*)(csum + 256 + lane * 4);
  float closs = 0.f, sloss = 0.f;
  for (int it = 0; it < 8; ++it) {
    int r = (blockIdx.x * 4 + wid) * 8 + it;
    float* Erow = out + SQ_OFF + (size_t)r * 512;
    float4v e0 = *(const float4v*)(Erow + lane * 4);
    float4v e1 = *(const float4v*)(Erow + 256 + lane * 4);
    // q row (bf16) — MUST be read before smbf store (aliased)
    ushort4v q0u = *(const ushort4v*)(qsm + (size_t)r * 512 + lane * 4);
    ushort4v q1u = *(const ushort4v*)(qsm + (size_t)r * 512 + 256 + lane * 4);
    float rsum = e0[0] + e0[1] + e0[2] + e0[3] + e1[0] + e1[1] + e1[2] + e1[3];
    #pragma unroll
    for (int off = 1; off < 64; off <<= 1) rsum += __shfl_xor(rsum, off);
    // top-2 (value, index), ties -> lower index
    float v1 = -1.f, v2 = -2.f; int i1 = 0, i2 = 0;
    #pragma unroll
    for (int j = 0; j < 4; ++j) {
      float val = e0[j]; int idx = lane * 4 + j;
      if (val > v1) { v2 = v1; i2 = i1; v1 = val; i1 = idx; }
      else if (val > v2) { v2 = val; i2 = idx; }
    }
    #pragma unroll
    for (int j = 0; j < 4; ++j) {
      float val = e1[j]; int idx = 256 + lane * 4 + j;
      if (val > v1) { v2 = v1; i2 = i1; v1 = val; i1 = idx; }
      else if (val > v2) { v2 = val; i2 = idx; }
    }
    #pragma unroll
    for (int off = 1; off < 64; off <<= 1) {
      float ov1 = __shfl_xor(v1, off); int oi1 = __shfl_xor(i1, off);
      float ov2 = __shfl_xor(v2, off); int oi2 = __shfl_xor(i2, off);
      bool take = (ov1 > v1) || (ov1 == v1 && oi1 < i1);
      float av = take ? v1 : v2;  int ai = take ? i1 : i2;
      float bv = take ? ov2 : ov1; int bi = take ? oi2 : oi1;
      bool t2 = (bv > av) || (bv == av && bi < ai);
      v2 = t2 ? bv : av; i2 = t2 ? bi : ai;
      v1 = take ? ov1 : v1; i1 = take ? oi1 : i1;
    }
    float invr = 1.0f / rsum;
    float4v sm0, sm1, sq0, sq1;
    #pragma unroll
    for (int j = 0; j < 4; ++j) {
      sm0[j] = e0[j] * invr; sm1[j] = e1[j] * invr;
      sq0[j] = e0[j] / c0[j]; sq1[j] = e1[j] / c1[j];
    }
    *(float4v*)(Erow + lane * 4) = sq0;              // overwrite E with score_q
    *(float4v*)(Erow + 256 + lane * 4) = sq1;
    float* SMrow = out + SM_OFF + (size_t)r * 512;
    *(float4v*)(SMrow + lane * 4) = sm0;
    *(float4v*)(SMrow + 256 + lane * 4) = sm1;
    ushort4v p0, p1;
    #pragma unroll
    for (int j = 0; j < 4; ++j) { p0[j] = f2bf(sm0[j]); p1[j] = f2bf(sm1[j]); }
    *(ushort4v*)(qsm + (size_t)r * 512 + lane * 4) = p0;        // smbf over qbf
    *(ushort4v*)(qsm + (size_t)r * 512 + 256 + lane * 4) = p1;
    // losses
    const float* prow = keys + (size_t)i1 * 512;
    const float* nrow = keys + (size_t)i2 * 512;
    float4v pp0 = *(const float4v*)(prow + lane * 4);
    float4v pp1 = *(const float4v*)(prow + 256 + lane * 4);
    float4v nn0 = *(const float4v*)(nrow + lane * 4);
    float4v nn1 = *(const float4v*)(nrow + 256 + lane * 4);
    float cp = 0.f, dp2 = 0.f, dn2 = 0.f;
    float qv0[4], qv1[4];
    #pragma unroll
    for (int j = 0; j < 4; ++j) {
      float q = bf2f(q0u[j]); qv0[j] = q;
      float dp = q - pp0[j]; cp += dp * dp;
      float t = dp + 1e-6f; dp2 += t * t;
      float dn = q - nn0[j] + 1e-6f; dn2 += dn * dn;
      q = bf2f(q1u[j]); qv1[j] = q;
      dp = q - pp1[j]; cp += dp * dp;
      t = dp + 1e-6f; dp2 += t * t;
      dn = q - nn1[j] + 1e-6f; dn2 += dn * dn;
    }
    #pragma unroll
    for (int off = 1; off < 64; off <<= 1) {
      cp += __shfl_xor(cp, off);
      dp2 += __shfl_xor(dp2, off);
      dn2 += __shfl_xor(dn2, off);
    }
    closs += cp;
    sloss += fmaxf(sqrtf(dp2) - sqrtf(dn2) + 1.0f, 0.f);
    // scatter: query_update[g] += q * wgt,  wgt = score_q[r, i1]
    float wgt = v1 / csum[i1];
    float* qrow = qu + (size_t)i1 * 512;
    #pragma unroll
    for (int j = 0; j < 4; ++j) atomicAdd(&qrow[lane * 4 + j], qv0[j] * wgt);
    #pragma unroll
    for (int j = 0; j < 4; ++j) atomicAdd(&qrow[256 + lane * 4 + j], qv1[j] * wgt);
  }
  if (lane == 0) {
    atomicAdd(out + SEP_OFF, sloss * (1.0f / 65536.0f));
    atomicAdd(out + COMP_OFF, closs * (1.0f / (65536.0f * 512.0f)));
  }
}

// ---------------- K5: GEMM2  updated_query[:,512:] = (score_m @ keys)^T per b ----------------
// C2T[d][hw] per b: A = ktbf (512 x 512, d rows, K=m contig), B = smbf rows (r, K=m contig)
__global__ __launch_bounds__(256) void k5_gemm2(
    const unsigned short* __restrict__ ktbf, const unsigned short* __restrict__ smbf,
    float* __restrict__ out) {
  __shared__ unsigned short As[128 * 32];
  __shared__ unsigned short Bs[128 * 32];
  int bid = blockIdx.x;                              // 2048
  int g = (bid & 7) * 64 + (bid >> 5);               // 0..511 -> (b, nt); siblings share A panel
  int b = g >> 5, nt = g & 31, dt = (bid >> 3) & 3;
  int tid = threadIdx.x;
  int lane = tid & 63, wid = tid >> 6;
  int wr = wid >> 1, wc = wid & 1;
  float4v acc[4][4];
  #pragma unroll
  for (int m = 0; m < 4; ++m)
    #pragma unroll
    for (int n = 0; n < 4; ++n) acc[m][n] = (float4v){0.f, 0.f, 0.f, 0.f};
  const unsigned short* Abase = ktbf + (size_t)dt * 128 * 512;
  const unsigned short* Bbase = smbf + (size_t)(b * 4096 + nt * 128) * 512;
  int u0 = wid * 128 + lane, u1 = u0 + 64;
  int ra0 = u0 >> 2, ca0 = (u0 & 3) * 8;
  int ra1 = u1 >> 2, ca1 = (u1 & 3) * 8;
  for (int kt = 0; kt < 16; ++kt) {
    const unsigned short* Ak = Abase + kt * 32;
    const unsigned short* Bk = Bbase + kt * 32;
    GLDS16(Ak + (size_t)ra0 * 512 + ca0, &As[(wid * 2 + 0) * 512]);
    GLDS16(Ak + (size_t)ra1 * 512 + ca1, &As[(wid * 2 + 1) * 512]);
    GLDS16(Bk + (size_t)ra0 * 512 + ca0, &Bs[(wid * 2 + 0) * 512]);
    GLDS16(Bk + (size_t)ra1 * 512 + ca1, &Bs[(wid * 2 + 1) * 512]);
    __syncthreads();
    short8v a[4], bb[4];
    const unsigned short* pa = As + (wr * 64 + (lane & 15)) * 32 + (lane >> 4) * 8;
    const unsigned short* pb = Bs + (wc * 64 + (lane & 15)) * 32 + (lane >> 4) * 8;
    #pragma unroll
    for (int m = 0; m < 4; ++m) a[m] = *(const short8v*)(pa + m * 512);
    #pragma unroll
    for (int n = 0; n < 4; ++n) bb[n] = *(const short8v*)(pb + n * 512);
    #pragma unroll
    for (int m = 0; m < 4; ++m)
      #pragma unroll
      for (int n = 0; n < 4; ++n)
        acc[m][n] = __builtin_amdgcn_mfma_f32_16x16x32_bf16(a[m], bb[n], acc[m][n], 0, 0, 0);
    __syncthreads();
  }
  // epilogue: out[b, 512 + d, hw]
  float* dst = out + (size_t)b * 4194304 + (size_t)512 * 4096;
  int d0 = dt * 128 + wr * 64 + (lane >> 4) * 4;
  int c0 = nt * 128 + wc * 64 + (lane & 15);
  #pragma unroll
  for (int m = 0; m < 4; ++m)
    #pragma unroll
    for (int n = 0; n < 4; ++n)
      #pragma unroll
      for (int j = 0; j < 4; ++j)
        dst[(size_t)(d0 + m * 16 + j) * 4096 + (c0 + n * 16)] = acc[m][n][j];
}

// ---------------- K6: updated_memory ----------------
__global__ void k6_mem(const float* __restrict__ keys, const float* __restrict__ qu,
                       float* __restrict__ out) {
  int m = blockIdx.x, lane = threadIdx.x;   // 512 blocks x 64
  const float4v k0 = *(const float4v*)(keys + (size_t)m * 512 + lane * 4);
  const float4v k1 = *(const float4v*)(keys + (size_t)m * 512 + 256 + lane * 4);
  const float4v u0 = *(const float4v*)(qu + (size_t)m * 512 + lane * 4);
  const float4v u1 = *(const float4v*)(qu + (size_t)m * 512 + 256 + lane * 4);
  float4v v0, v1;
  float ss = 0.f;
  #pragma unroll
  for (int j = 0; j < 4; ++j) {
    v0[j] = k0[j] * 0.999f + u0[j] * 0.001f; ss += v0[j] * v0[j];
    v1[j] = k1[j] * 0.999f + u1[j] * 0.001f; ss += v1[j] * v1[j];
  }
  #pragma unroll
  for (int off = 1; off < 64; off <<= 1) ss += __shfl_xor(ss, off);
  float rsn = 1.0f / fmaxf(sqrtf(ss), 1e-12f);
  float* dst = out + UM_OFF + (size_t)m * 512;
  float4v o0, o1;
  #pragma unroll
  for (int j = 0; j < 4; ++j) { o0[j] = v0[j] * rsn; o1[j] = v1[j] * rsn; }
  *(float4v*)(dst + lane * 4) = o0;
  *(float4v*)(dst + 256 + lane * 4) = o1;
}

extern "C" void kernel_launch(void* const* d_in, const int* in_sizes, int n_in,
                              void* d_out, int out_size, void* d_ws, size_t ws_size,
                              hipStream_t stream) {
  const float* query = (const float*)d_in[0];
  const float* keys  = (const float*)d_in[1];
  float* out = (float*)d_out;
  char* ws = (char*)d_ws;
  unsigned short* qsm  = (unsigned short*)(ws + WS_QBF);   // qbf, then smbf in-place
  unsigned short* kbf  = (unsigned short*)(ws + WS_KBF);
  unsigned short* ktbf = (unsigned short*)(ws + WS_KTBF);
  float* qu   = (float*)(ws + WS_QU);
  float* csum = (float*)(ws + WS_CSUM);

  k0_prep<<<dim3(1024), dim3(256), 0, stream>>>(keys, kbf, ktbf, qu, csum, out);
  k1_norm<<<dim3(1024), dim3(256), 0, stream>>>(query, out, qsm);
  k3_gemm1<<<dim3(2048), dim3(256), 0, stream>>>(qsm, kbf, out, csum);
  k4_rows<<<dim3(2048), dim3(256), 0, stream>>>(out, csum, qsm, keys, qu);
  k5_gemm2<<<dim3(2048), dim3(256), 0, stream>>>(ktbf, qsm, out);
  k6_mem<<<dim3(512), dim3(64), 0, stream>>>(keys, qu, out);
}

// Round 4
// 595.045 us; speedup vs baseline: 1.3063x; 1.3063x over previous
//
#include <hip/hip_runtime.h>
#include <stdint.h>

// Problem: B=16, D=512, H=64, W=64, M=512, N=B*H*W=65536
// out layout (floats):
//   updated_query  [0, 67108864)          (16,1024,64,64)
//   updated_memory [67108864, 67371008)   (512,512)
//   score_q        [67371008, 100925440)  (65536,512)
//   score_m        [100925440, 134479872) (65536,512)
//   separateness   [134479872]
//   compactness    [134479873]
#define UM_OFF   67108864u
#define SQ_OFF   67371008u
#define SM_OFF   100925440u
#define SEP_OFF  134479872u
#define COMP_OFF 134479873u

// ws layout (bytes) — total ~65.6 MiB
#define WS_QBF   0u           // 65536*512 bf16 = 64 MiB (q rows, kept valid to the end)
#define WS_KBF   67108864u    // keys bf16 (M,D)        512 KiB -> ends 67633152
#define WS_KTBF  67633152u    // keysT bf16 (D,M)       512 KiB -> ends 68157440
#define WS_G     68157440u    // g[r] int32             262144 B -> ends 68419584
#define WS_W     68419584u    // wgt[r] f32             262144 B -> ends 68681728
#define WS_CSUM  68681728u    // col sums f32 (512)     (round-3 bug: was 68675584, overlapped gw!)

typedef __attribute__((ext_vector_type(8))) short short8v;
typedef __attribute__((ext_vector_type(4))) float float4v;
typedef __attribute__((ext_vector_type(4))) unsigned short ushort4v;

__device__ __forceinline__ unsigned short f2bf(float f) {
  union { float f; uint32_t u; } v; v.f = f;
  return (unsigned short)((v.u + 0x7fffu + ((v.u >> 16) & 1u)) >> 16);
}
__device__ __forceinline__ float bf2f(unsigned short s) {
  union { uint32_t u; float f; } v; v.u = ((uint32_t)s) << 16;
  return v.f;
}

#define GLDS16(gp, lp) __builtin_amdgcn_global_load_lds( \
    (__attribute__((address_space(1))) const void*)(gp), \
    (__attribute__((address_space(3))) void*)(lp), 16, 0, 0)

// ---------------- K0: prep (bf16 keys, keysT, zero accumulators) ----------------
__global__ void k0_prep(const float* __restrict__ keys, unsigned short* __restrict__ kbf,
                        unsigned short* __restrict__ ktbf,
                        float* __restrict__ csum, float* __restrict__ out) {
  int i = blockIdx.x * 256 + threadIdx.x;   // 262144 threads exactly
  kbf[i] = f2bf(keys[i]);
  int d = i >> 9, m = i & 511;              // ktbf[i] = keysT[d][m] = keys[m][d]
  ktbf[i] = f2bf(keys[(size_t)m * 512 + d]);
  if (i < 512) csum[i] = 0.0f;
  if (i < 2) out[SEP_OFF + i] = 0.0f;
}

// ---------------- K1: per-pixel L2 norm, write updated_query[:, :512], write qbf ----------------
// one block per (b,h): tile is query[b, 0:512, h, 0:64]
__global__ __launch_bounds__(256) void k1_norm(const float* __restrict__ query,
                                               float* __restrict__ out,
                                               unsigned short* __restrict__ qbf) {
  __shared__ unsigned short vals[512 * 65];  // [d][w], pad 65 (bank spread)
  __shared__ float pp[4][64];
  __shared__ float rs[64];
  int bh = blockIdx.x;                       // b*64 + h
  int b = bh >> 6, h = bh & 63;
  int tid = threadIdx.x;
  int w = tid & 63, dg = tid >> 6;
  const float* src = query + ((size_t)(b * 512) * 64 + h) * 64 + w;  // + d*4096
  float ss = 0.f;
  #pragma unroll 4
  for (int i = 0; i < 128; ++i) {
    int d = dg * 128 + i;
    float v = src[(size_t)d * 4096];
    ss += v * v;
    vals[d * 65 + w] = f2bf(v);
  }
  pp[dg][w] = ss;
  __syncthreads();
  if (tid < 64) {
    float s = pp[0][tid] + pp[1][tid] + pp[2][tid] + pp[3][tid];
    rs[tid] = 1.0f / fmaxf(sqrtf(s), 1e-12f);
  }
  __syncthreads();
  // phase B: updated_query[b, d, h, w] = qn (coalesced)
  float rw_ = rs[w];
  float* dst = out + ((size_t)(b * 1024) * 64 + h) * 64 + w;
  #pragma unroll 4
  for (int i = 0; i < 128; ++i) {
    int d = dg * 128 + i;
    dst[(size_t)d * 4096] = bf2f(vals[d * 65 + w]) * rw_;
  }
  // phase C: qbf[r][d] transposed write, r = bh*64 + w2
  int w2 = tid >> 2, dc = tid & 3;
  float rw = rs[w2];
  unsigned short* qrow = qbf + ((size_t)bh * 64 + w2) * 512;
  #pragma unroll
  for (int g = 0; g < 8; ++g) {
    int d0 = g * 64 + dc * 16;
    short8v pk0, pk1;
    #pragma unroll
    for (int jj = 0; jj < 8; ++jj) {
      pk0[jj] = (short)f2bf(bf2f(vals[(d0 + jj) * 65 + w2]) * rw);
      pk1[jj] = (short)f2bf(bf2f(vals[(d0 + 8 + jj) * 65 + w2]) * rw);
    }
    *(short8v*)(qrow + d0) = pk0;
    *(short8v*)(qrow + d0 + 8) = pk1;
  }
}

// ---------------- K3: GEMM1  E = exp(q @ keys^T / scale), col-sum atomics ----------------
// C[r][m], A=qbf (65536x512), B=kbf (512x512, N x K row-major). 128x128 tile, BK=32.
__global__ __launch_bounds__(256) void k3_gemm1(
    const unsigned short* __restrict__ qbf, const unsigned short* __restrict__ kbf,
    float* __restrict__ out, float* __restrict__ csum) {
  __shared__ unsigned short As[128 * 32];
  __shared__ unsigned short Bs[128 * 32];
  int bid = blockIdx.x;                          // 2048
  int bm = (bid & 7) * 64 + (bid >> 5);          // siblings (same XCD) share B panel
  int bn = (bid >> 3) & 3;
  int tid = threadIdx.x;
  int lane = tid & 63, wid = tid >> 6;
  int wr = wid >> 1, wc = wid & 1;
  float4v acc[4][4];
  #pragma unroll
  for (int m = 0; m < 4; ++m)
    #pragma unroll
    for (int n = 0; n < 4; ++n) acc[m][n] = (float4v){0.f, 0.f, 0.f, 0.f};
  const unsigned short* Abase = qbf + (size_t)bm * 128 * 512;
  const unsigned short* Bbase = kbf + (size_t)bn * 128 * 512;
  int u0 = wid * 128 + lane, u1 = u0 + 64;       // 16B staging units
  int ra0 = u0 >> 2, ca0 = (u0 & 3) * 8;
  int ra1 = u1 >> 2, ca1 = (u1 & 3) * 8;
  for (int kt = 0; kt < 16; ++kt) {
    const unsigned short* Ak = Abase + kt * 32;
    const unsigned short* Bk = Bbase + kt * 32;
    GLDS16(Ak + (size_t)ra0 * 512 + ca0, &As[(wid * 2 + 0) * 512]);
    GLDS16(Ak + (size_t)ra1 * 512 + ca1, &As[(wid * 2 + 1) * 512]);
    GLDS16(Bk + (size_t)ra0 * 512 + ca0, &Bs[(wid * 2 + 0) * 512]);
    GLDS16(Bk + (size_t)ra1 * 512 + ca1, &Bs[(wid * 2 + 1) * 512]);
    __syncthreads();
    short8v a[4], b[4];
    const unsigned short* pa = As + (wr * 64 + (lane & 15)) * 32 + (lane >> 4) * 8;
    const unsigned short* pb = Bs + (wc * 64 + (lane & 15)) * 32 + (lane >> 4) * 8;
    #pragma unroll
    for (int m = 0; m < 4; ++m) a[m] = *(const short8v*)(pa + m * 512);
    #pragma unroll
    for (int n = 0; n < 4; ++n) b[n] = *(const short8v*)(pb + n * 512);
    #pragma unroll
    for (int m = 0; m < 4; ++m)
      #pragma unroll
      for (int n = 0; n < 4; ++n)
        acc[m][n] = __builtin_amdgcn_mfma_f32_16x16x32_bf16(a[m], b[n], acc[m][n], 0, 0, 0);
    __syncthreads();
  }
  // epilogue: E = exp(logit/scale) into score_q region; column partial sums
  float* E = out + SQ_OFF;
  const float inv_scale = 0.44194173824159216f;  // 1/(sqrt(512)*0.1)
  int r0 = bm * 128 + wr * 64 + (lane >> 4) * 4;
  int c0 = bn * 128 + wc * 64 + (lane & 15);
  float cs[4] = {0.f, 0.f, 0.f, 0.f};
  #pragma unroll
  for (int m = 0; m < 4; ++m)
    #pragma unroll
    for (int n = 0; n < 4; ++n)
      #pragma unroll
      for (int j = 0; j < 4; ++j) {
        float v = __expf(acc[m][n][j] * inv_scale);
        E[(size_t)(r0 + m * 16 + j) * 512 + (c0 + n * 16)] = v;
        cs[n] += v;
      }
  #pragma unroll
  for (int n = 0; n < 4; ++n) {
    float v = cs[n];
    v += __shfl_xor(v, 16);
    v += __shfl_xor(v, 32);
    if ((lane >> 4) == 0) atomicAdd(&csum[c0 + n * 16], v);
  }
}

// ---------------- K4: per-row pass ----------------
// Writes score_q (over E, in place), score_m (f32), per-row (g, wgt); loss atomics.
// NO element-wise scatter atomics; qbf left intact.
__global__ __launch_bounds__(256) void k4_rows(
    float* __restrict__ out, const float* __restrict__ csum,
    const unsigned short* __restrict__ qbf, const float* __restrict__ keys,
    int* __restrict__ gidx, float* __restrict__ gw) {
  int tid = threadIdx.x;
  int lane = tid & 63, wid = tid >> 6;
  float4v c0 = *(const float4v*)(csum + lane * 4);
  float4v c1 = *(const float4v*)(csum + 256 + lane * 4);
  float closs = 0.f, sloss = 0.f;
  for (int it = 0; it < 8; ++it) {
    int r = (blockIdx.x * 4 + wid) * 8 + it;
    float* Erow = out + SQ_OFF + (size_t)r * 512;
    float4v e0 = *(const float4v*)(Erow + lane * 4);
    float4v e1 = *(const float4v*)(Erow + 256 + lane * 4);
    ushort4v q0u = *(const ushort4v*)(qbf + (size_t)r * 512 + lane * 4);
    ushort4v q1u = *(const ushort4v*)(qbf + (size_t)r * 512 + 256 + lane * 4);
    float rsum = e0[0] + e0[1] + e0[2] + e0[3] + e1[0] + e1[1] + e1[2] + e1[3];
    #pragma unroll
    for (int off = 1; off < 64; off <<= 1) rsum += __shfl_xor(rsum, off);
    // top-2 (value, index), ties -> lower index
    float v1 = -1.f, v2 = -2.f; int i1 = 0, i2 = 0;
    #pragma unroll
    for (int j = 0; j < 4; ++j) {
      float val = e0[j]; int idx = lane * 4 + j;
      if (val > v1) { v2 = v1; i2 = i1; v1 = val; i1 = idx; }
      else if (val > v2) { v2 = val; i2 = idx; }
    }
    #pragma unroll
    for (int j = 0; j < 4; ++j) {
      float val = e1[j]; int idx = 256 + lane * 4 + j;
      if (val > v1) { v2 = v1; i2 = i1; v1 = val; i1 = idx; }
      else if (val > v2) { v2 = val; i2 = idx; }
    }
    #pragma unroll
    for (int off = 1; off < 64; off <<= 1) {
      float ov1 = __shfl_xor(v1, off); int oi1 = __shfl_xor(i1, off);
      float ov2 = __shfl_xor(v2, off); int oi2 = __shfl_xor(i2, off);
      bool take = (ov1 > v1) || (ov1 == v1 && oi1 < i1);
      float av = take ? v1 : v2;  int ai = take ? i1 : i2;
      float bv = take ? ov2 : ov1; int bi = take ? oi2 : oi1;
      bool t2 = (bv > av) || (bv == av && bi < ai);
      v2 = t2 ? bv : av; i2 = t2 ? bi : ai;
      v1 = take ? ov1 : v1; i1 = take ? oi1 : i1;
    }
    float invr = 1.0f / rsum;
    float4v sm0, sm1, sq0, sq1;
    #pragma unroll
    for (int j = 0; j < 4; ++j) {
      sm0[j] = e0[j] * invr; sm1[j] = e1[j] * invr;
      sq0[j] = e0[j] / c0[j]; sq1[j] = e1[j] / c1[j];
    }
    *(float4v*)(Erow + lane * 4) = sq0;              // overwrite E with score_q
    *(float4v*)(Erow + 256 + lane * 4) = sq1;
    float* SMrow = out + SM_OFF + (size_t)r * 512;
    *(float4v*)(SMrow + lane * 4) = sm0;
    *(float4v*)(SMrow + 256 + lane * 4) = sm1;
    // per-row segment info
    if (lane == 0) { gidx[r] = i1; gw[r] = v1 / csum[i1]; }
    // losses
    const float* prow = keys + (size_t)i1 * 512;
    const float* nrow = keys + (size_t)i2 * 512;
    float4v pp0 = *(const float4v*)(prow + lane * 4);
    float4v pp1 = *(const float4v*)(prow + 256 + lane * 4);
    float4v nn0 = *(const float4v*)(nrow + lane * 4);
    float4v nn1 = *(const float4v*)(nrow + 256 + lane * 4);
    float cp = 0.f, dp2 = 0.f, dn2 = 0.f;
    #pragma unroll
    for (int j = 0; j < 4; ++j) {
      float q = bf2f(q0u[j]);
      float dp = q - pp0[j]; cp += dp * dp;
      float t = dp + 1e-6f; dp2 += t * t;
      float dn = q - nn0[j] + 1e-6f; dn2 += dn * dn;
      q = bf2f(q1u[j]);
      dp = q - pp1[j]; cp += dp * dp;
      t = dp + 1e-6f; dp2 += t * t;
      dn = q - nn1[j] + 1e-6f; dn2 += dn * dn;
    }
    #pragma unroll
    for (int off = 1; off < 64; off <<= 1) {
      cp += __shfl_xor(cp, off);
      dp2 += __shfl_xor(dp2, off);
      dn2 += __shfl_xor(dn2, off);
    }
    closs += cp;
    sloss += fmaxf(sqrtf(dp2) - sqrtf(dn2) + 1.0f, 0.f);
  }
  if (lane == 0) {
    atomicAdd(out + SEP_OFF, sloss * (1.0f / 65536.0f));
    atomicAdd(out + COMP_OFF, closs * (1.0f / (65536.0f * 512.0f)));
  }
}

// ---------------- K4b: segment gather + memory update (replaces atomics + K6) ----------------
// one block per memory slot m; 4 waves scan disjoint quarters of g[], gather q rows.
__global__ __launch_bounds__(256) void k4b_gather(
    const int* __restrict__ gidx, const float* __restrict__ gw,
    const unsigned short* __restrict__ qbf, const float* __restrict__ keys,
    float* __restrict__ out) {
  __shared__ float red[4][512];
  __shared__ float wss[4];
  int m = blockIdx.x;                 // 512
  int tid = threadIdx.x, lane = tid & 63, wid = tid >> 6;
  float acc[8] = {0.f, 0.f, 0.f, 0.f, 0.f, 0.f, 0.f, 0.f};
  // wave wid scans rows [wid*16384, (wid+1)*16384)
  for (int c = 0; c < 256; ++c) {
    int r0 = wid * 16384 + c * 64;
    int gv = gidx[r0 + lane];
    unsigned long long mask = __ballot(gv == m);
    while (mask) {
      int b = __ffsll((long long)mask) - 1;
      mask &= mask - 1;
      int r = r0 + b;
      float wv = gw[r];
      short8v qv = *(const short8v*)(qbf + (size_t)r * 512 + lane * 8);
      #pragma unroll
      for (int j = 0; j < 8; ++j) acc[j] += wv * bf2f((unsigned short)qv[j]);
    }
  }
  #pragma unroll
  for (int j = 0; j < 8; ++j) red[wid][lane * 8 + j] = acc[j];
  __syncthreads();
  // memory update: um[m] = l2norm(keys[m]*0.999 + qu*0.001)
  int d0 = tid, d1 = tid + 256;
  float s0 = red[0][d0] + red[1][d0] + red[2][d0] + red[3][d0];
  float s1 = red[0][d1] + red[1][d1] + red[2][d1] + red[3][d1];
  float v0 = keys[(size_t)m * 512 + d0] * 0.999f + s0 * 0.001f;
  float v1 = keys[(size_t)m * 512 + d1] * 0.999f + s1 * 0.001f;
  float ss = v0 * v0 + v1 * v1;
  #pragma unroll
  for (int off = 1; off < 64; off <<= 1) ss += __shfl_xor(ss, off);
  if (lane == 0) wss[wid] = ss;
  __syncthreads();
  float tot = wss[0] + wss[1] + wss[2] + wss[3];
  float rs = 1.0f / fmaxf(sqrtf(tot), 1e-12f);
  out[UM_OFF + (size_t)m * 512 + d0] = v0 * rs;
  out[UM_OFF + (size_t)m * 512 + d1] = v1 * rs;
}

// ---------------- K5: GEMM2  updated_query[:,512:] = (score_m @ keys)^T per b ----------------
// A = ktbf (bf16, GLDS16); B = score_m f32 rows from out, reg-staged + converted to bf16.
__global__ __launch_bounds__(256) void k5_gemm2(
    const unsigned short* __restrict__ ktbf, const float* __restrict__ smf,
    float* __restrict__ out) {
  __shared__ unsigned short As[128 * 32];
  __shared__ unsigned short Bs[128 * 32];
  int bid = blockIdx.x;                              // 2048
  int g = (bid & 7) * 64 + (bid >> 5);               // 0..511 -> (b, nt); XCD siblings share B panel
  int b = g >> 5, nt = g & 31, dt = (bid >> 3) & 3;
  int tid = threadIdx.x;
  int lane = tid & 63, wid = tid >> 6;
  int wr = wid >> 1, wc = wid & 1;
  float4v acc[4][4];
  #pragma unroll
  for (int m = 0; m < 4; ++m)
    #pragma unroll
    for (int n = 0; n < 4; ++n) acc[m][n] = (float4v){0.f, 0.f, 0.f, 0.f};
  const unsigned short* Abase = ktbf + (size_t)dt * 128 * 512;
  const float* Bbase = smf + (size_t)(b * 4096 + nt * 128) * 512;
  int u0 = wid * 128 + lane, u1 = u0 + 64;
  int ra0 = u0 >> 2, ca0 = (u0 & 3) * 8;
  int ra1 = u1 >> 2, ca1 = (u1 & 3) * 8;
  for (int kt = 0; kt < 16; ++kt) {
    const unsigned short* Ak = Abase + kt * 32;
    GLDS16(Ak + (size_t)ra0 * 512 + ca0, &As[(wid * 2 + 0) * 512]);
    GLDS16(Ak + (size_t)ra1 * 512 + ca1, &As[(wid * 2 + 1) * 512]);
    // B: reg-stage f32 -> bf16 -> LDS (linear [row][32])
    #pragma unroll
    for (int p = 0; p < 4; ++p) {
      int idx = p * 256 + tid;
      int row = idx >> 3, c4 = (idx & 7) * 4;
      float4v bv = *(const float4v*)(Bbase + (size_t)row * 512 + kt * 32 + c4);
      ushort4v bb;
      #pragma unroll
      for (int j = 0; j < 4; ++j) bb[j] = f2bf(bv[j]);
      *(ushort4v*)(&Bs[row * 32 + c4]) = bb;
    }
    __syncthreads();
    short8v a[4], bb2[4];
    const unsigned short* pa = As + (wr * 64 + (lane & 15)) * 32 + (lane >> 4) * 8;
    const unsigned short* pb = Bs + (wc * 64 + (lane & 15)) * 32 + (lane >> 4) * 8;
    #pragma unroll
    for (int m = 0; m < 4; ++m) a[m] = *(const short8v*)(pa + m * 512);
    #pragma unroll
    for (int n = 0; n < 4; ++n) bb2[n] = *(const short8v*)(pb + n * 512);
    #pragma unroll
    for (int m = 0; m < 4; ++m)
      #pragma unroll
      for (int n = 0; n < 4; ++n)
        acc[m][n] = __builtin_amdgcn_mfma_f32_16x16x32_bf16(a[m], bb2[n], acc[m][n], 0, 0, 0);
    __syncthreads();
  }
  // epilogue: out[b, 512 + d, hw]
  float* dst = out + (size_t)b * 4194304 + (size_t)512 * 4096;
  int d0 = dt * 128 + wr * 64 + (lane >> 4) * 4;
  int c0 = nt * 128 + wc * 64 + (lane & 15);
  #pragma unroll
  for (int m = 0; m < 4; ++m)
    #pragma unroll
    for (int n = 0; n < 4; ++n)
      #pragma unroll
      for (int j = 0; j < 4; ++j)
        dst[(size_t)(d0 + m * 16 + j) * 4096 + (c0 + n * 16)] = acc[m][n][j];
}

extern "C" void kernel_launch(void* const* d_in, const int* in_sizes, int n_in,
                              void* d_out, int out_size, void* d_ws, size_t ws_size,
                              hipStream_t stream) {
  const float* query = (const float*)d_in[0];
  const float* keys  = (const float*)d_in[1];
  float* out = (float*)d_out;
  char* ws = (char*)d_ws;
  unsigned short* qbf  = (unsigned short*)(ws + WS_QBF);
  unsigned short* kbf  = (unsigned short*)(ws + WS_KBF);
  unsigned short* ktbf = (unsigned short*)(ws + WS_KTBF);
  int*   gidx = (int*)(ws + WS_G);
  float* gw   = (float*)(ws + WS_W);
  float* csum = (float*)(ws + WS_CSUM);

  k0_prep<<<dim3(1024), dim3(256), 0, stream>>>(keys, kbf, ktbf, csum, out);
  k1_norm<<<dim3(1024), dim3(256), 0, stream>>>(query, out, qbf);
  k3_gemm1<<<dim3(2048), dim3(256), 0, stream>>>(qbf, kbf, out, csum);
  k4_rows<<<dim3(2048), dim3(256), 0, stream>>>(out, csum, qbf, keys, gidx, gw);
  k4b_gather<<<dim3(512), dim3(256), 0, stream>>>(gidx, gw, qbf, keys, out);
  k5_gemm2<<<dim3(2048), dim3(256), 0, stream>>>(ktbf, out + SM_OFF, out);
}

// Round 5
// 514.595 us; speedup vs baseline: 1.5105x; 1.1563x over previous
//
#include <hip/hip_runtime.h>
#include <stdint.h>

// Problem: B=16, D=512, H=64, W=64, M=512, N=B*H*W=65536
// out layout (floats):
//   updated_query  [0, 67108864)          (16,1024,64,64)
//   updated_memory [67108864, 67371008)   (512,512)
//   score_q        [67371008, 100925440)  (65536,512)
//   score_m        [100925440, 134479872) (65536,512)
//   separateness   [134479872] | compactness [134479873]
#define UM_OFF   67108864u
#define SQ_OFF   67371008u
#define SM_OFF   100925440u
#define SEP_OFF  134479872u
#define COMP_OFF 134479873u

// ws layout (bytes) — ~65.8 MiB
#define WS_QBF   0u           // 65536*512 bf16 = 64 MiB (q rows, pristine to the end)
#define WS_KBF   67108864u    // keys bf16 (M,D)   -> 67633152
#define WS_KTBF  67633152u    // keysT bf16 (D,M)  -> 68157440
#define WS_G     68157440u    // g[r] int32 (65536) -> 68419584
#define WS_W     68419584u    // wgt[r] f32 (65536) -> 68681728
#define WS_RSUM  68681728u    // rsum[r] f32 (65536) -> 68943872
#define WS_CSUM  68943872u    // csum f32 (512)

// Ebf convention: bf16 E row r lives in the FIRST 1024 B of score_q's f32 row
// slot (out + SQ_OFF + r*512 floats). k4 later overwrites each slot with f32
// score_q AFTER reading its own row (one wave owns one row -> no hazard).

typedef __attribute__((ext_vector_type(8))) short short8v;
typedef __attribute__((ext_vector_type(4))) float float4v;

__device__ __forceinline__ unsigned short f2bf(float f) {
  union { float f; uint32_t u; } v; v.f = f;
  return (unsigned short)((v.u + 0x7fffu + ((v.u >> 16) & 1u)) >> 16);
}
__device__ __forceinline__ float bf2f(unsigned short s) {
  union { uint32_t u; float f; } v; v.u = ((uint32_t)s) << 16;
  return v.f;
}

#define GLDS16(gp, lp) __builtin_amdgcn_global_load_lds( \
    (__attribute__((address_space(1))) const void*)(gp), \
    (__attribute__((address_space(3))) void*)(lp), 16, 0, 0)

// ---------------- K0: prep ----------------
__global__ void k0_prep(const float* __restrict__ keys, unsigned short* __restrict__ kbf,
                        unsigned short* __restrict__ ktbf, float* __restrict__ csum,
                        float* __restrict__ rsum, float* __restrict__ out) {
  int i = blockIdx.x * 256 + threadIdx.x;   // 262144 threads exactly
  kbf[i] = f2bf(keys[i]);
  int d = i >> 9, m = i & 511;
  ktbf[i] = f2bf(keys[(size_t)m * 512 + d]);
  if (i < 65536) rsum[i] = 0.0f;
  if (i < 512) csum[i] = 0.0f;
  if (i < 2) out[SEP_OFF + i] = 0.0f;
}

// ---------------- K1: per-pixel L2 norm (512 thr: 2 blk/CU = 4 waves/SIMD) ----------------
__global__ __launch_bounds__(512) void k1_norm(const float* __restrict__ query,
                                               float* __restrict__ out,
                                               unsigned short* __restrict__ qbf) {
  __shared__ unsigned short vals[512 * 65];
  __shared__ float pp[8][64];
  __shared__ float rs[64];
  int bh = blockIdx.x;                       // b*64 + h
  int b = bh >> 6, h = bh & 63;
  int tid = threadIdx.x;
  int w = tid & 63, dg = tid >> 6;           // 8 d-groups of 64
  const float* src = query + ((size_t)(b * 512) * 64 + h) * 64 + w;
  float ss = 0.f;
  #pragma unroll 4
  for (int i = 0; i < 64; ++i) {
    int d = dg * 64 + i;
    float v = src[(size_t)d * 4096];
    ss += v * v;
    vals[d * 65 + w] = f2bf(v);
  }
  pp[dg][w] = ss;
  __syncthreads();
  if (tid < 64) {
    float s = 0.f;
    #pragma unroll
    for (int g = 0; g < 8; ++g) s += pp[g][tid];
    rs[tid] = 1.0f / fmaxf(sqrtf(s), 1e-12f);
  }
  __syncthreads();
  float rw_ = rs[w];
  float* dst = out + ((size_t)(b * 1024) * 64 + h) * 64 + w;
  #pragma unroll 4
  for (int i = 0; i < 64; ++i) {
    int d = dg * 64 + i;
    dst[(size_t)d * 4096] = bf2f(vals[d * 65 + w]) * rw_;
  }
  // phase C: qbf[r][d], r = bh*64 + w2; d0 = g*64 + dc*8 (dc fast -> ~2-way banks)
  int w2 = tid >> 3, dc = tid & 7;
  float rw = rs[w2];
  unsigned short* qrow = qbf + ((size_t)bh * 64 + w2) * 512;
  #pragma unroll
  for (int g = 0; g < 8; ++g) {
    int d0 = g * 64 + dc * 8;
    short8v pk;
    #pragma unroll
    for (int jj = 0; jj < 8; ++jj)
      pk[jj] = (short)f2bf(bf2f(vals[(d0 + jj) * 65 + w2]) * rw);
    *(short8v*)(qrow + d0) = pk;
  }
}

// ---------------- K3: GEMM1 -> Ebf (interleaved), csum + rsum atomics ----------------
__global__ __launch_bounds__(256) void k3_gemm1(
    const unsigned short* __restrict__ qbf, const unsigned short* __restrict__ kbf,
    float* __restrict__ out, float* __restrict__ csum, float* __restrict__ rsum) {
  __shared__ unsigned short As[128 * 32];
  __shared__ unsigned short Bs[128 * 32];
  int bid = blockIdx.x;                          // 2048
  int bm = (bid & 7) * 64 + (bid >> 5);          // XCD siblings share B panel
  int bn = (bid >> 3) & 3;
  int tid = threadIdx.x;
  int lane = tid & 63, wid = tid >> 6;
  int wr = wid >> 1, wc = wid & 1;
  float4v acc[4][4];
  #pragma unroll
  for (int m = 0; m < 4; ++m)
    #pragma unroll
    for (int n = 0; n < 4; ++n) acc[m][n] = (float4v){0.f, 0.f, 0.f, 0.f};
  const unsigned short* Abase = qbf + (size_t)bm * 128 * 512;
  const unsigned short* Bbase = kbf + (size_t)bn * 128 * 512;
  int u0 = wid * 128 + lane, u1 = u0 + 64;
  int ra0 = u0 >> 2, ca0 = (u0 & 3) * 8;
  int ra1 = u1 >> 2, ca1 = (u1 & 3) * 8;
  for (int kt = 0; kt < 16; ++kt) {
    const unsigned short* Ak = Abase + kt * 32;
    const unsigned short* Bk = Bbase + kt * 32;
    GLDS16(Ak + (size_t)ra0 * 512 + ca0, &As[(wid * 2 + 0) * 512]);
    GLDS16(Ak + (size_t)ra1 * 512 + ca1, &As[(wid * 2 + 1) * 512]);
    GLDS16(Bk + (size_t)ra0 * 512 + ca0, &Bs[(wid * 2 + 0) * 512]);
    GLDS16(Bk + (size_t)ra1 * 512 + ca1, &Bs[(wid * 2 + 1) * 512]);
    __syncthreads();
    short8v a[4], b[4];
    const unsigned short* pa = As + (wr * 64 + (lane & 15)) * 32 + (lane >> 4) * 8;
    const unsigned short* pb = Bs + (wc * 64 + (lane & 15)) * 32 + (lane >> 4) * 8;
    #pragma unroll
    for (int m = 0; m < 4; ++m) a[m] = *(const short8v*)(pa + m * 512);
    #pragma unroll
    for (int n = 0; n < 4; ++n) b[n] = *(const short8v*)(pb + n * 512);
    #pragma unroll
    for (int m = 0; m < 4; ++m)
      #pragma unroll
      for (int n = 0; n < 4; ++n)
        acc[m][n] = __builtin_amdgcn_mfma_f32_16x16x32_bf16(a[m], b[n], acc[m][n], 0, 0, 0);
    __syncthreads();
  }
  // epilogue: Ebf = bf16(exp(logit/scale)); csum (col) + rsum (row) atomics
  float* E = out + SQ_OFF;
  const float inv_scale = 0.44194173824159216f;  // 1/(sqrt(512)*0.1)
  int r0 = bm * 128 + wr * 64 + (lane >> 4) * 4;
  int c0 = bn * 128 + wc * 64 + (lane & 15);
  float cs[4] = {0.f, 0.f, 0.f, 0.f};
  float rp[4][4];
  #pragma unroll
  for (int m = 0; m < 4; ++m)
    #pragma unroll
    for (int j = 0; j < 4; ++j) rp[m][j] = 0.f;
  #pragma unroll
  for (int m = 0; m < 4; ++m)
    #pragma unroll
    for (int n = 0; n < 4; ++n)
      #pragma unroll
      for (int j = 0; j < 4; ++j) {
        float v = __expf(acc[m][n][j] * inv_scale);
        int r = r0 + m * 16 + j;
        ((unsigned short*)(E + (size_t)r * 512))[c0 + n * 16] = f2bf(v);
        cs[n] += v;
        rp[m][j] += v;
      }
  #pragma unroll
  for (int n = 0; n < 4; ++n) {
    float v = cs[n];
    v += __shfl_xor(v, 16);
    v += __shfl_xor(v, 32);
    if ((lane >> 4) == 0) atomicAdd(&csum[c0 + n * 16], v);
  }
  // row partials: butterfly within each 16-lane group (same rows)
  #pragma unroll
  for (int m = 0; m < 4; ++m)
    #pragma unroll
    for (int j = 0; j < 4; ++j) {
      float v = rp[m][j];
      v += __shfl_xor(v, 1); v += __shfl_xor(v, 2);
      v += __shfl_xor(v, 4); v += __shfl_xor(v, 8);
      rp[m][j] = v;
    }
  int g16 = lane & 15;
  float myrp = 0.f;
  #pragma unroll
  for (int m = 0; m < 4; ++m)
    #pragma unroll
    for (int j = 0; j < 4; ++j)
      if (g16 == m * 4 + j) myrp = rp[m][j];   // static-index select
  atomicAdd(&rsum[r0 + (g16 >> 2) * 16 + (g16 & 3)], myrp);
}

// ---------------- K5: GEMM2 (runs BEFORE k4) ----------------
// C2[d][r] = sum_m ktbf[d][m]*Ebf[r][m], scaled by 1/rsum[r] -> uq[:,512:]
__global__ __launch_bounds__(256) void k5_gemm2(
    const unsigned short* __restrict__ ktbf, const unsigned short* __restrict__ ebase,
    const float* __restrict__ rsum, float* __restrict__ out) {
  __shared__ unsigned short As[128 * 32];
  __shared__ unsigned short Bs[128 * 32];
  int bid = blockIdx.x;                              // 2048
  int g = (bid & 7) * 64 + (bid >> 5);               // (b,nt); XCD siblings share B panel
  int b = g >> 5, nt = g & 31, dt = (bid >> 3) & 3;
  int tid = threadIdx.x;
  int lane = tid & 63, wid = tid >> 6;
  int wr = wid >> 1, wc = wid & 1;
  float4v acc[4][4];
  #pragma unroll
  for (int m = 0; m < 4; ++m)
    #pragma unroll
    for (int n = 0; n < 4; ++n) acc[m][n] = (float4v){0.f, 0.f, 0.f, 0.f};
  const unsigned short* Abase = ktbf + (size_t)dt * 128 * 512;
  size_t brow0 = (size_t)(b * 4096 + nt * 128);
  int u0 = wid * 128 + lane, u1 = u0 + 64;
  int ra0 = u0 >> 2, ca0 = (u0 & 3) * 8;
  int ra1 = u1 >> 2, ca1 = (u1 & 3) * 8;
  for (int kt = 0; kt < 16; ++kt) {
    GLDS16(Abase + (size_t)ra0 * 512 + kt * 32 + ca0, &As[(wid * 2 + 0) * 512]);
    GLDS16(Abase + (size_t)ra1 * 512 + kt * 32 + ca1, &As[(wid * 2 + 1) * 512]);
    // B rows from interleaved Ebf: row slot stride = 1024 ushorts
    GLDS16(ebase + (brow0 + ra0) * 1024 + kt * 32 + ca0, &Bs[(wid * 2 + 0) * 512]);
    GLDS16(ebase + (brow0 + ra1) * 1024 + kt * 32 + ca1, &Bs[(wid * 2 + 1) * 512]);
    __syncthreads();
    short8v a[4], bb[4];
    const unsigned short* pa = As + (wr * 64 + (lane & 15)) * 32 + (lane >> 4) * 8;
    const unsigned short* pb = Bs + (wc * 64 + (lane & 15)) * 32 + (lane >> 4) * 8;
    #pragma unroll
    for (int m = 0; m < 4; ++m) a[m] = *(const short8v*)(pa + m * 512);
    #pragma unroll
    for (int n = 0; n < 4; ++n) bb[n] = *(const short8v*)(pb + n * 512);
    #pragma unroll
    for (int m = 0; m < 4; ++m)
      #pragma unroll
      for (int n = 0; n < 4; ++n)
        acc[m][n] = __builtin_amdgcn_mfma_f32_16x16x32_bf16(a[m], bb[n], acc[m][n], 0, 0, 0);
    __syncthreads();
  }
  float* dst = out + (size_t)b * 4194304 + (size_t)512 * 4096;
  int d0 = dt * 128 + wr * 64 + (lane >> 4) * 4;
  int c0 = nt * 128 + wc * 64 + (lane & 15);
  float invc[4];
  #pragma unroll
  for (int n = 0; n < 4; ++n) invc[n] = 1.0f / rsum[b * 4096 + c0 + n * 16];
  #pragma unroll
  for (int m = 0; m < 4; ++m)
    #pragma unroll
    for (int n = 0; n < 4; ++n)
      #pragma unroll
      for (int j = 0; j < 4; ++j)
        dst[(size_t)(d0 + m * 16 + j) * 4096 + (c0 + n * 16)] = acc[m][n][j] * invc[n];
}

// ---------------- K4: per-row pass (reads Ebf, writes sq f32 in place + sm f32) ----------------
__global__ __launch_bounds__(256) void k4_rows(
    float* __restrict__ out, const float* __restrict__ csum,
    const unsigned short* __restrict__ qbf, const float* __restrict__ keys,
    int* __restrict__ gidx, float* __restrict__ gw) {
  int tid = threadIdx.x;
  int lane = tid & 63, wid = tid >> 6;
  float4v cA = *(const float4v*)(csum + lane * 8);
  float4v cB = *(const float4v*)(csum + lane * 8 + 4);
  float4v rcA, rcB;
  #pragma unroll
  for (int j = 0; j < 4; ++j) { rcA[j] = 1.0f / cA[j]; rcB[j] = 1.0f / cB[j]; }
  float closs = 0.f, sloss = 0.f;
  for (int it = 0; it < 8; ++it) {
    int r = (blockIdx.x * 4 + wid) * 8 + it;
    float* slot = out + SQ_OFF + (size_t)r * 512;
    short8v eb = *(const short8v*)((const unsigned short*)slot + lane * 8);
    short8v qv = *(const short8v*)(qbf + (size_t)r * 512 + lane * 8);
    float e[8];
    #pragma unroll
    for (int j = 0; j < 8; ++j) e[j] = bf2f((unsigned short)eb[j]);
    float rsum = e[0] + e[1] + e[2] + e[3] + e[4] + e[5] + e[6] + e[7];
    #pragma unroll
    for (int off = 1; off < 64; off <<= 1) rsum += __shfl_xor(rsum, off);
    // top-2 (ties -> lower index)
    float v1 = -1.f, v2 = -2.f; int i1 = 0, i2 = 0;
    #pragma unroll
    for (int j = 0; j < 8; ++j) {
      float val = e[j]; int idx = lane * 8 + j;
      if (val > v1) { v2 = v1; i2 = i1; v1 = val; i1 = idx; }
      else if (val > v2) { v2 = val; i2 = idx; }
    }
    #pragma unroll
    for (int off = 1; off < 64; off <<= 1) {
      float ov1 = __shfl_xor(v1, off); int oi1 = __shfl_xor(i1, off);
      float ov2 = __shfl_xor(v2, off); int oi2 = __shfl_xor(i2, off);
      bool take = (ov1 > v1) || (ov1 == v1 && oi1 < i1);
      float av = take ? v1 : v2;  int ai = take ? i1 : i2;
      float bv = take ? ov2 : ov1; int bi = take ? oi2 : oi1;
      bool t2 = (bv > av) || (bv == av && bi < ai);
      v2 = t2 ? bv : av; i2 = t2 ? bi : ai;
      v1 = take ? ov1 : v1; i1 = take ? oi1 : i1;
    }
    float invr = 1.0f / rsum;
    float4v sq0, sq1, sm0, sm1;
    #pragma unroll
    for (int j = 0; j < 4; ++j) {
      sq0[j] = e[j] * rcA[j];     sq1[j] = e[4 + j] * rcB[j];
      sm0[j] = e[j] * invr;       sm1[j] = e[4 + j] * invr;
    }
    *(float4v*)(slot + lane * 8) = sq0;        // overwrites Ebf AFTER the read
    *(float4v*)(slot + lane * 8 + 4) = sq1;
    float* SMrow = out + SM_OFF + (size_t)r * 512;
    *(float4v*)(SMrow + lane * 8) = sm0;
    *(float4v*)(SMrow + lane * 8 + 4) = sm1;
    if (lane == 0) { gidx[r] = i1; gw[r] = v1 / csum[i1]; }
    // losses
    const float* prow = keys + (size_t)i1 * 512;
    const float* nrow = keys + (size_t)i2 * 512;
    float4v pp0 = *(const float4v*)(prow + lane * 8);
    float4v pp1 = *(const float4v*)(prow + lane * 8 + 4);
    float4v nn0 = *(const float4v*)(nrow + lane * 8);
    float4v nn1 = *(const float4v*)(nrow + lane * 8 + 4);
    float cp = 0.f, dp2 = 0.f, dn2 = 0.f;
    #pragma unroll
    for (int j = 0; j < 4; ++j) {
      float q = bf2f((unsigned short)qv[j]);
      float dp = q - pp0[j]; cp += dp * dp;
      float t = dp + 1e-6f; dp2 += t * t;
      float dn = q - nn0[j] + 1e-6f; dn2 += dn * dn;
      q = bf2f((unsigned short)qv[4 + j]);
      dp = q - pp1[j]; cp += dp * dp;
      t = dp + 1e-6f; dp2 += t * t;
      dn = q - nn1[j] + 1e-6f; dn2 += dn * dn;
    }
    #pragma unroll
    for (int off = 1; off < 64; off <<= 1) {
      cp += __shfl_xor(cp, off);
      dp2 += __shfl_xor(dp2, off);
      dn2 += __shfl_xor(dn2, off);
    }
    closs += cp;
    sloss += fmaxf(sqrtf(dp2) - sqrtf(dn2) + 1.0f, 0.f);
  }
  if (lane == 0) {
    atomicAdd(out + SEP_OFF, sloss * (1.0f / 65536.0f));
    atomicAdd(out + COMP_OFF, closs * (1.0f / (65536.0f * 512.0f)));
  }
}

// ---------------- K4b: segment gather + memory update (512 thr) ----------------
__global__ __launch_bounds__(512) void k4b_gather(
    const int* __restrict__ gidx, const float* __restrict__ gw,
    const unsigned short* __restrict__ qbf, const float* __restrict__ keys,
    float* __restrict__ out) {
  __shared__ float red[8][512];
  __shared__ float wss[8];
  int m = blockIdx.x;                 // 512
  int tid = threadIdx.x, lane = tid & 63, wid = tid >> 6;
  float acc[8] = {0.f, 0.f, 0.f, 0.f, 0.f, 0.f, 0.f, 0.f};
  for (int c = 0; c < 128; ++c) {
    int r0 = wid * 8192 + c * 64;
    int gv = gidx[r0 + lane];
    unsigned long long mask = __ballot(gv == m);
    while (mask) {
      int bb = __ffsll((long long)mask) - 1;
      mask &= mask - 1;
      int r = r0 + bb;
      float wv = gw[r];
      short8v qv = *(const short8v*)(qbf + (size_t)r * 512 + lane * 8);
      #pragma unroll
      for (int j = 0; j < 8; ++j) acc[j] += wv * bf2f((unsigned short)qv[j]);
    }
  }
  #pragma unroll
  for (int j = 0; j < 8; ++j) red[wid][lane * 8 + j] = acc[j];
  __syncthreads();
  int d0 = tid;                        // 0..511
  float s = 0.f;
  #pragma unroll
  for (int g = 0; g < 8; ++g) s += red[g][d0];
  float v = keys[(size_t)m * 512 + d0] * 0.999f + s * 0.001f;
  float ss = v * v;
  #pragma unroll
  for (int off = 1; off < 64; off <<= 1) ss += __shfl_xor(ss, off);
  if (lane == 0) wss[wid] = ss;
  __syncthreads();
  float tot = 0.f;
  #pragma unroll
  for (int g = 0; g < 8; ++g) tot += wss[g];
  float rsn = 1.0f / fmaxf(sqrtf(tot), 1e-12f);
  out[UM_OFF + (size_t)m * 512 + d0] = v * rsn;
}

extern "C" void kernel_launch(void* const* d_in, const int* in_sizes, int n_in,
                              void* d_out, int out_size, void* d_ws, size_t ws_size,
                              hipStream_t stream) {
  const float* query = (const float*)d_in[0];
  const float* keys  = (const float*)d_in[1];
  float* out = (float*)d_out;
  char* ws = (char*)d_ws;
  unsigned short* qbf  = (unsigned short*)(ws + WS_QBF);
  unsigned short* kbf  = (unsigned short*)(ws + WS_KBF);
  unsigned short* ktbf = (unsigned short*)(ws + WS_KTBF);
  int*   gidx = (int*)(ws + WS_G);
  float* gw   = (float*)(ws + WS_W);
  float* rsum = (float*)(ws + WS_RSUM);
  float* csum = (float*)(ws + WS_CSUM);

  k0_prep<<<dim3(1024), dim3(256), 0, stream>>>(keys, kbf, ktbf, csum, rsum, out);
  k1_norm<<<dim3(1024), dim3(512), 0, stream>>>(query, out, qbf);
  k3_gemm1<<<dim3(2048), dim3(256), 0, stream>>>(qbf, kbf, out, csum, rsum);
  k5_gemm2<<<dim3(2048), dim3(256), 0, stream>>>(
      ktbf, (const unsigned short*)(out + SQ_OFF), rsum, out);
  k4_rows<<<dim3(2048), dim3(256), 0, stream>>>(out, csum, qbf, keys, gidx, gw);
  k4b_gather<<<dim3(512), dim3(512), 0, stream>>>(gidx, gw, qbf, keys, out);
}